// Round 1
// baseline (1323.831 us; speedup 1.0000x reference)
//
#include <hip/hip_runtime.h>
#include <stdint.h>

// BatchTopK: x (1024, 65536) f32, keep global top k*1024 = 65536 of relu(x), zero rest.
//
// Strategy: fused [read x -> zero out -> speculative compact of v>=3.0] single pass,
// exact 3-level radix select over ~90k candidates in one block, sparse scatter.
// Flag-gated exact single-block fallback (full radix over all data) guarantees
// correctness for any input / tiny ws; never taken for the fixed bench input.

#define HDR_CURSOR 0
#define HDR_FLAG   1
#define HDR_THR    2
#define HDR_ICUT   3
#define CAND_OFF   4096       // byte offset of candidate buffer in ws
#define LDS_STAGE  2048       // per-block candidate staging (expected ~44/block)
#define ROWS       1024u      // x.shape[0], fixed by the problem
#define SPEC       3.0f       // speculation threshold: count(x>=3.0) ~ 90.6k >= K=65536

// Wave-aggregated LDS histogram add: one LDS atomic per distinct bin per wave.
// All 64 lanes of each wave must reach this call (loop bounds kept wave-uniform).
__device__ __forceinline__ void hist_add_agg(uint32_t* hist, uint32_t bin, bool valid) {
  unsigned long long mask = __ballot(valid ? 1 : 0);
  int lane = (int)(threadIdx.x & 63u);
  while (mask) {
    int leader = __builtin_ctzll(mask);
    uint32_t lb = (uint32_t)__shfl((int)bin, leader, 64);
    unsigned long long eq = __ballot((valid && bin == lb) ? 1 : 0);
    if (lane == leader) atomicAdd(&hist[lb], (uint32_t)__popcll(eq));
    mask &= ~eq;
    if (valid && bin == lb) valid = false;
  }
}

__global__ void k_init(uint32_t* hdr, uint32_t force_flag) {
  if (threadIdx.x < 64u) hdr[threadIdx.x] = 0u;
  if (threadIdx.x == 0u) hdr[HDR_FLAG] = force_flag;
}

// Read x (float4), write out=0 densely, append (bits,idx) of v>=SPEC to ws.
__global__ __launch_bounds__(256) void k_compact(
    const float4* __restrict__ x4, float4* __restrict__ out4,
    const float* __restrict__ x, float* __restrict__ out,
    uint2* __restrict__ cand, uint32_t* __restrict__ hdr,
    uint32_t cap, uint32_t n4, uint32_t n) {
  __shared__ uint32_t s_cnt;
  __shared__ uint32_t s_base;
  __shared__ uint2 s_buf[LDS_STAGE];
  if (threadIdx.x == 0u) s_cnt = 0u;
  __syncthreads();

  uint32_t stride = gridDim.x * blockDim.x;
  for (uint32_t i = blockIdx.x * blockDim.x + threadIdx.x; i < n4; i += stride) {
    float4 v = x4[i];
    out4[i] = make_float4(0.f, 0.f, 0.f, 0.f);
    uint32_t gi = i * 4u;
    if (v.x >= SPEC) { uint32_t p = atomicAdd(&s_cnt, 1u); if (p < LDS_STAGE) s_buf[p] = make_uint2(__float_as_uint(v.x), gi); }
    if (v.y >= SPEC) { uint32_t p = atomicAdd(&s_cnt, 1u); if (p < LDS_STAGE) s_buf[p] = make_uint2(__float_as_uint(v.y), gi + 1u); }
    if (v.z >= SPEC) { uint32_t p = atomicAdd(&s_cnt, 1u); if (p < LDS_STAGE) s_buf[p] = make_uint2(__float_as_uint(v.z), gi + 2u); }
    if (v.w >= SPEC) { uint32_t p = atomicAdd(&s_cnt, 1u); if (p < LDS_STAGE) s_buf[p] = make_uint2(__float_as_uint(v.w), gi + 3u); }
  }
  // tail (n not multiple of 4 — not the case here, but correct anyway)
  uint32_t tail0 = n4 * 4u;
  if (blockIdx.x == 0u && threadIdx.x < (n - tail0)) {
    uint32_t gi = tail0 + threadIdx.x;
    float v = x[gi];
    out[gi] = 0.f;
    if (v >= SPEC) { uint32_t p = atomicAdd(&s_cnt, 1u); if (p < LDS_STAGE) s_buf[p] = make_uint2(__float_as_uint(v), gi); }
  }
  __syncthreads();
  uint32_t cnt = s_cnt;
  if (cnt == 0u) return;
  uint32_t wcnt = cnt < (uint32_t)LDS_STAGE ? cnt : (uint32_t)LDS_STAGE;
  if (threadIdx.x == 0u) {
    s_base = atomicAdd(&hdr[HDR_CURSOR], cnt);  // true total (dropped entries flagged)
    if (cnt > (uint32_t)LDS_STAGE) atomicOr(&hdr[HDR_FLAG], 1u);
  }
  __syncthreads();
  uint32_t base = s_base;
  for (uint32_t j = threadIdx.x; j < wcnt; j += blockDim.x) {
    uint32_t g = base + j;
    if (g < cap) cand[g] = s_buf[j];
  }
  if (threadIdx.x == 0u && base + wcnt > cap) atomicOr(&hdr[HDR_FLAG], 1u);
}

// Single block: exact K-th largest among candidates via 3-level radix (11/11/10 bits),
// stable tie cut (T-th smallest index among equals). Sets HDR_THR / HDR_ICUT.
__global__ __launch_bounds__(1024) void k_select(
    const uint2* __restrict__ cand, uint32_t* __restrict__ hdr,
    const int* __restrict__ kptr, uint32_t cap) {
  __shared__ uint32_t hist[2048];
  __shared__ uint32_t s_sel, s_rank, s_eqcnt, s_icut;
  __shared__ uint32_t eq_idx[4096];
  uint32_t tid = threadIdx.x;
  uint32_t K = (uint32_t)kptr[0] * ROWS;
  uint32_t M = hdr[HDR_CURSOR];
  if (hdr[HDR_FLAG] != 0u || M > cap || M < K) {
    if (tid == 0u) hdr[HDR_FLAG] = 1u;
    return;
  }
  uint32_t R = K;        // 1-indexed rank within current subset
  uint32_t prefix = 0u;  // accumulated high bits of the threshold key
  for (int lvl = 0; lvl < 3; ++lvl) {
    uint32_t shift = (lvl == 0) ? 21u : (lvl == 1 ? 10u : 0u);
    uint32_t nb = (lvl == 2) ? 1024u : 2048u;
    for (uint32_t b = tid; b < nb; b += blockDim.x) hist[b] = 0u;
    __syncthreads();
    for (uint32_t i0 = 0; i0 < M; i0 += blockDim.x) {
      uint32_t i = i0 + tid;
      bool in = i < M;
      uint32_t key = in ? cand[i].x : 0u;
      bool valid = in;
      if (lvl == 1) valid = valid && ((key >> 21) == prefix);
      if (lvl == 2) valid = valid && ((key >> 10) == prefix);
      uint32_t bin = (key >> shift) & (nb - 1u);
      hist_add_agg(hist, bin, valid);
    }
    __syncthreads();
    if (tid == 0u) {
      uint32_t cum = 0u, sel = 0u, rr = R;
      for (int b = (int)nb - 1; b >= 0; --b) {
        uint32_t c = hist[b];
        if (cum + c >= R) { sel = (uint32_t)b; rr = R - cum; break; }
        cum += c;
      }
      s_sel = sel; s_rank = rr;
    }
    __syncthreads();
    uint32_t sel = s_sel;
    R = s_rank;
    if (lvl == 0) prefix = sel;
    else if (lvl == 1) prefix = (prefix << 11) | sel;
    else prefix = (prefix << 10) | sel;
    __syncthreads();
  }
  uint32_t thr_key = prefix;
  uint32_t E = hist[thr_key & 1023u];  // count of keys == thr among candidates
  uint32_t T = R;                      // how many equals to keep (lowest indices)
  uint32_t icut = 0xFFFFFFFFu;
  if (T < E) {
    if (tid == 0u) { s_eqcnt = 0u; s_icut = 0xFFFFFFFFu; }
    __syncthreads();
    for (uint32_t i0 = 0; i0 < M; i0 += blockDim.x) {
      uint32_t i = i0 + tid;
      if (i < M) {
        uint2 c = cand[i];
        if (c.x == thr_key) { uint32_t p = atomicAdd(&s_eqcnt, 1u); if (p < 4096u) eq_idx[p] = c.y; }
      }
    }
    __syncthreads();
    uint32_t ec = s_eqcnt < 4096u ? s_eqcnt : 4096u;
    for (uint32_t e = tid; e < ec; e += blockDim.x) {
      uint32_t me = eq_idx[e];
      uint32_t rank = 0u;
      for (uint32_t j = 0; j < ec; ++j) rank += (eq_idx[j] < me) ? 1u : 0u;
      if (rank == T - 1u) s_icut = me;   // T-th smallest equal index
    }
    __syncthreads();
    icut = s_icut;
  }
  if (tid == 0u) { hdr[HDR_THR] = thr_key; hdr[HDR_ICUT] = icut; }
}

// Sparse scatter of kept candidates into the pre-zeroed output.
__global__ __launch_bounds__(256) void k_scatter(
    const uint2* __restrict__ cand, const uint32_t* __restrict__ hdr,
    float* __restrict__ out, uint32_t cap) {
  if (hdr[HDR_FLAG] != 0u) return;
  uint32_t M = hdr[HDR_CURSOR]; if (M > cap) M = cap;
  uint32_t thr = hdr[HDR_THR], icut = hdr[HDR_ICUT];
  uint32_t stride = gridDim.x * blockDim.x;
  for (uint32_t i = blockIdx.x * blockDim.x + threadIdx.x; i < M; i += stride) {
    uint2 c = cand[i];
    if (c.x > thr || (c.x == thr && c.y <= icut)) out[c.y] = __uint_as_float(c.x);
  }
}

// Exact general fallback (gated; never taken for the fixed bench input).
// Single block, full radix select over all data + dense rewrite. Slow but correct.
__global__ __launch_bounds__(1024) void k_fallback(
    const float* __restrict__ x, float* __restrict__ out,
    const int* __restrict__ kptr, const uint32_t* __restrict__ hdr, uint32_t n) {
  if (hdr[HDR_FLAG] == 0u) return;
  __shared__ uint32_t hist[2048];
  __shared__ uint32_t s_sel, s_rank, s_found, s_eqcnt, s_icut;
  __shared__ uint32_t eq_idx[4096];
  uint32_t tid = threadIdx.x;
  uint32_t K = (uint32_t)kptr[0] * ROWS;
  uint32_t prefix = 0u;
  uint32_t R = K;
  bool zero_thr = false;
  for (int lvl = 0; lvl < 3; ++lvl) {
    if (zero_thr) break;
    uint32_t shift = (lvl == 0) ? 21u : (lvl == 1 ? 10u : 0u);
    uint32_t nb = (lvl == 2) ? 1024u : 2048u;
    for (uint32_t b = tid; b < nb; b += blockDim.x) hist[b] = 0u;
    __syncthreads();
    for (uint32_t i0 = 0; i0 < n; i0 += blockDim.x) {
      uint32_t i = i0 + tid;
      bool in = i < n;
      float v = in ? x[i] : 0.f;
      uint32_t key = (v > 0.f) ? __float_as_uint(v) : 0u;
      bool valid = in && key != 0u;
      if (lvl == 1) valid = valid && ((key >> 21) == prefix);
      if (lvl == 2) valid = valid && ((key >> 10) == prefix);
      uint32_t bin = (key >> shift) & (nb - 1u);
      hist_add_agg(hist, bin, valid);
    }
    __syncthreads();
    if (tid == 0u) {
      uint32_t cum = 0u, sel = 0u, rr = R, found = 0u;
      for (int b = (int)nb - 1; b >= 0; --b) {
        uint32_t c = hist[b];
        if (cum + c >= R) { sel = (uint32_t)b; rr = R - cum; found = 1u; break; }
        cum += c;
      }
      s_sel = sel; s_rank = rr; s_found = found;
    }
    __syncthreads();
    if (s_found == 0u) {
      zero_thr = true;  // fewer than K positives: keep all positives
    } else {
      uint32_t sel = s_sel;
      R = s_rank;
      if (lvl == 0) prefix = sel;
      else if (lvl == 1) prefix = (prefix << 11) | sel;
      else prefix = (prefix << 10) | sel;
    }
    __syncthreads();
  }
  uint32_t thr_key = zero_thr ? 0u : prefix;
  uint32_t icut = 0xFFFFFFFFu;
  if (!zero_thr) {
    uint32_t E = hist[thr_key & 1023u];
    uint32_t T = R;
    if (T < E) {
      if (tid == 0u) { s_eqcnt = 0u; s_icut = 0xFFFFFFFFu; }
      __syncthreads();
      for (uint32_t i0 = 0; i0 < n; i0 += blockDim.x) {
        uint32_t i = i0 + tid;
        if (i < n) {
          float v = x[i];
          if (v > 0.f && __float_as_uint(v) == thr_key) {
            uint32_t p = atomicAdd(&s_eqcnt, 1u);
            if (p < 4096u) eq_idx[p] = i;
          }
        }
      }
      __syncthreads();
      uint32_t ec = s_eqcnt < 4096u ? s_eqcnt : 4096u;
      for (uint32_t e = tid; e < ec; e += blockDim.x) {
        uint32_t me = eq_idx[e];
        uint32_t rank = 0u;
        for (uint32_t j = 0; j < ec; ++j) rank += (eq_idx[j] < me) ? 1u : 0u;
        if (rank == T - 1u) s_icut = me;
      }
      __syncthreads();
      icut = s_icut;
    }
  }
  for (uint32_t i0 = 0; i0 < n; i0 += blockDim.x) {
    uint32_t i = i0 + tid;
    if (i < n) {
      float v = x[i];
      uint32_t key = (v > 0.f) ? __float_as_uint(v) : 0u;
      bool keep = (key > thr_key) || (key != 0u && key == thr_key && i <= icut);
      out[i] = keep ? v : 0.f;
    }
  }
}

extern "C" void kernel_launch(void* const* d_in, const int* in_sizes, int n_in,
                              void* d_out, int out_size, void* d_ws, size_t ws_size,
                              hipStream_t stream) {
  const float* x = (const float*)d_in[0];
  const int* kptr = (const int*)d_in[1];
  float* out = (float*)d_out;
  uint32_t n = (uint32_t)in_sizes[0];
  uint32_t n4 = n >> 2;

  uint32_t* hdr = (uint32_t*)d_ws;
  uint2* cand = (uint2*)((char*)d_ws + CAND_OFF);
  uint32_t cap = (ws_size > (size_t)CAND_OFF) ? (uint32_t)((ws_size - CAND_OFF) / 8) : 0u;
  // If ws can't hold candidates with margin, force the exact fallback path.
  uint32_t force = (cap < 131072u) ? 1u : 0u;

  k_init<<<1, 64, 0, stream>>>(hdr, force);
  k_compact<<<2048, 256, 0, stream>>>((const float4*)x, (float4*)out, x, out,
                                      cand, hdr, cap, n4, n);
  k_select<<<1, 1024, 0, stream>>>(cand, hdr, kptr, cap);
  k_fallback<<<1, 1024, 0, stream>>>(x, out, kptr, hdr, n);
  k_scatter<<<256, 256, 0, stream>>>(cand, hdr, out, cap);
}

// Round 2
// 572.097 us; speedup vs baseline: 2.3140x; 2.3140x over previous
//
#include <hip/hip_runtime.h>
#include <stdint.h>

// BatchTopK: x (1024, 65536) f32, keep global top k*1024 = 65536 of relu(x), zero rest.
//
// R2: k_select rebuilt — plain LDS atomics (m136: N-way conflict ~ N/2.8 cyc,
// far cheaper than ballot-aggregation loops), uint4 candidate loads, and a
// wave-parallel suffix scan for the rank bin. Fallback simplified likewise.

#define HDR_CURSOR 0
#define HDR_FLAG   1
#define HDR_THR    2
#define HDR_ICUT   3
#define CAND_OFF   4096       // byte offset of candidate buffer in ws
#define LDS_STAGE  2048       // per-block candidate staging (expected ~44/block)
#define ROWS       1024u      // x.shape[0], fixed by the problem
#define SPEC       3.0f       // speculation threshold: count(x>=3.0) ~ 90.6k >= K=65536

__global__ void k_init(uint32_t* hdr, uint32_t force_flag) {
  if (threadIdx.x < 64u) hdr[threadIdx.x] = 0u;
  if (threadIdx.x == 0u) hdr[HDR_FLAG] = force_flag;
}

// Read x (float4), write out=0 densely, append (bits,idx) of v>=SPEC to ws.
__global__ __launch_bounds__(256) void k_compact(
    const float4* __restrict__ x4, float4* __restrict__ out4,
    const float* __restrict__ x, float* __restrict__ out,
    uint2* __restrict__ cand, uint32_t* __restrict__ hdr,
    uint32_t cap, uint32_t n4, uint32_t n) {
  __shared__ uint32_t s_cnt;
  __shared__ uint32_t s_base;
  __shared__ uint2 s_buf[LDS_STAGE];
  if (threadIdx.x == 0u) s_cnt = 0u;
  __syncthreads();

  uint32_t stride = gridDim.x * blockDim.x;
  for (uint32_t i = blockIdx.x * blockDim.x + threadIdx.x; i < n4; i += stride) {
    float4 v = x4[i];
    out4[i] = make_float4(0.f, 0.f, 0.f, 0.f);
    uint32_t gi = i * 4u;
    if (v.x >= SPEC) { uint32_t p = atomicAdd(&s_cnt, 1u); if (p < LDS_STAGE) s_buf[p] = make_uint2(__float_as_uint(v.x), gi); }
    if (v.y >= SPEC) { uint32_t p = atomicAdd(&s_cnt, 1u); if (p < LDS_STAGE) s_buf[p] = make_uint2(__float_as_uint(v.y), gi + 1u); }
    if (v.z >= SPEC) { uint32_t p = atomicAdd(&s_cnt, 1u); if (p < LDS_STAGE) s_buf[p] = make_uint2(__float_as_uint(v.z), gi + 2u); }
    if (v.w >= SPEC) { uint32_t p = atomicAdd(&s_cnt, 1u); if (p < LDS_STAGE) s_buf[p] = make_uint2(__float_as_uint(v.w), gi + 3u); }
  }
  // tail (n not multiple of 4 — not the case here, but correct anyway)
  uint32_t tail0 = n4 * 4u;
  if (blockIdx.x == 0u && threadIdx.x < (n - tail0)) {
    uint32_t gi = tail0 + threadIdx.x;
    float v = x[gi];
    out[gi] = 0.f;
    if (v >= SPEC) { uint32_t p = atomicAdd(&s_cnt, 1u); if (p < LDS_STAGE) s_buf[p] = make_uint2(__float_as_uint(v), gi); }
  }
  __syncthreads();
  uint32_t cnt = s_cnt;
  if (cnt == 0u) return;
  uint32_t wcnt = cnt < (uint32_t)LDS_STAGE ? cnt : (uint32_t)LDS_STAGE;
  if (threadIdx.x == 0u) {
    s_base = atomicAdd(&hdr[HDR_CURSOR], cnt);  // true total (dropped entries flagged)
    if (cnt > (uint32_t)LDS_STAGE) atomicOr(&hdr[HDR_FLAG], 1u);
  }
  __syncthreads();
  uint32_t base = s_base;
  for (uint32_t j = threadIdx.x; j < wcnt; j += blockDim.x) {
    uint32_t g = base + j;
    if (g < cap) cand[g] = s_buf[j];
  }
  if (threadIdx.x == 0u && base + wcnt > cap) atomicOr(&hdr[HDR_FLAG], 1u);
}

// Single block: exact K-th largest among candidates via 3-level radix (11/11/10 bits).
// Plain LDS atomics + wave-parallel suffix scan. Stable tie cut via T-th smallest index.
__global__ __launch_bounds__(1024) void k_select(
    const uint2* __restrict__ cand, uint32_t* __restrict__ hdr,
    const int* __restrict__ kptr, uint32_t cap) {
  __shared__ uint32_t hist[2048];
  __shared__ uint32_t s_sel, s_rank, s_eqcnt, s_icut;
  __shared__ uint32_t eq_idx[4096];
  uint32_t tid = threadIdx.x;
  uint32_t K = (uint32_t)kptr[0] * ROWS;
  uint32_t M = hdr[HDR_CURSOR];
  if (hdr[HDR_FLAG] != 0u || M > cap || M < K) {
    if (tid == 0u) hdr[HDR_FLAG] = 1u;
    return;
  }
  if (K == 0u) {  // keep nothing; no candidate key can be 0xFFFFFFFF (all >= 3.0)
    if (tid == 0u) { hdr[HDR_THR] = 0xFFFFFFFFu; hdr[HDR_ICUT] = 0xFFFFFFFFu; }
    return;
  }
  const uint4* __restrict__ cand4 = (const uint4*)cand;
  uint32_t M2 = M >> 1;
  uint32_t R = K;        // 1-indexed rank within current subset
  uint32_t prefix = 0u;  // accumulated high bits of the threshold key
  for (int lvl = 0; lvl < 3; ++lvl) {
    uint32_t shift = (lvl == 0) ? 21u : (lvl == 1 ? 10u : 0u);
    uint32_t nb = (lvl == 2) ? 1024u : 2048u;
    for (uint32_t b = tid; b < nb; b += 1024u) hist[b] = 0u;
    __syncthreads();
    for (uint32_t j = tid; j < M2; j += 1024u) {
      uint4 c = cand4[j];                 // two candidates: keys c.x and c.z
      uint32_t k0 = c.x, k1 = c.z;
      bool v0 = true, v1 = true;
      if (lvl == 1) { v0 = ((k0 >> 21) == prefix); v1 = ((k1 >> 21) == prefix); }
      if (lvl == 2) { v0 = ((k0 >> 10) == prefix); v1 = ((k1 >> 10) == prefix); }
      if (v0) atomicAdd(&hist[(k0 >> shift) & (nb - 1u)], 1u);
      if (v1) atomicAdd(&hist[(k1 >> shift) & (nb - 1u)], 1u);
    }
    if (tid == 0u && (M & 1u)) {
      uint32_t key = cand[M - 1u].x;
      bool v = true;
      if (lvl == 1) v = ((key >> 21) == prefix);
      if (lvl == 2) v = ((key >> 10) == prefix);
      if (v) atomicAdd(&hist[(key >> shift) & (nb - 1u)], 1u);
    }
    __syncthreads();
    // wave 0: parallel suffix scan over nb bins to find the bin holding rank R
    if (tid < 64u) {
      uint32_t seg = nb >> 6;            // bins per lane: 32 or 16
      uint32_t base = tid * seg;
      uint32_t lanesum = 0u;
      for (uint32_t j = 0; j < seg; ++j) lanesum += hist[base + j];
      uint32_t s = lanesum;              // inclusive suffix scan across lanes
      for (int d = 1; d < 64; d <<= 1) {
        uint32_t v = (uint32_t)__shfl_down((int)s, d, 64);
        if ((int)tid + d < 64) s += v;
      }
      uint32_t above = s - lanesum;      // total count in lanes > tid
      if (above < R && above + lanesum >= R) {   // exactly one lane
        uint32_t r = R - above;
        uint32_t cum = 0u;
        for (int j = (int)seg - 1; j >= 0; --j) {
          uint32_t c = hist[base + (uint32_t)j];
          if (cum + c >= r) { s_sel = base + (uint32_t)j; s_rank = r - cum; break; }
          cum += c;
        }
      }
    }
    __syncthreads();
    uint32_t sel = s_sel;
    R = s_rank;
    if (lvl == 0) prefix = sel;
    else if (lvl == 1) prefix = (prefix << 11) | sel;
    else prefix = (prefix << 10) | sel;
  }
  uint32_t thr_key = prefix;
  uint32_t E = hist[thr_key & 1023u];  // count of keys == thr among candidates
  uint32_t T = R;                      // how many equals to keep (lowest indices)
  uint32_t icut = 0xFFFFFFFFu;
  if (T < E) {
    if (tid == 0u) { s_eqcnt = 0u; s_icut = 0xFFFFFFFFu; }
    __syncthreads();
    for (uint32_t i = tid; i < M; i += 1024u) {
      uint2 c = cand[i];
      if (c.x == thr_key) { uint32_t p = atomicAdd(&s_eqcnt, 1u); if (p < 4096u) eq_idx[p] = c.y; }
    }
    __syncthreads();
    if (s_eqcnt > 4096u) {             // can't rank ties exactly here -> exact fallback
      if (tid == 0u) hdr[HDR_FLAG] = 1u;
      return;
    }
    uint32_t ec = s_eqcnt;
    for (uint32_t e = tid; e < ec; e += 1024u) {
      uint32_t me = eq_idx[e];
      uint32_t rank = 0u;
      for (uint32_t j = 0; j < ec; ++j) rank += (eq_idx[j] < me) ? 1u : 0u;
      if (rank == T - 1u) s_icut = me;   // T-th smallest equal index
    }
    __syncthreads();
    icut = s_icut;
  }
  if (tid == 0u) { hdr[HDR_THR] = thr_key; hdr[HDR_ICUT] = icut; }
}

// Sparse scatter of kept candidates into the pre-zeroed output.
__global__ __launch_bounds__(256) void k_scatter(
    const uint2* __restrict__ cand, const uint32_t* __restrict__ hdr,
    float* __restrict__ out, uint32_t cap) {
  if (hdr[HDR_FLAG] != 0u) return;
  uint32_t M = hdr[HDR_CURSOR]; if (M > cap) M = cap;
  uint32_t thr = hdr[HDR_THR], icut = hdr[HDR_ICUT];
  uint32_t stride = gridDim.x * blockDim.x;
  for (uint32_t i = blockIdx.x * blockDim.x + threadIdx.x; i < M; i += stride) {
    uint2 c = cand[i];
    if (c.x > thr || (c.x == thr && c.y <= icut)) out[c.y] = __uint_as_float(c.x);
  }
}

// Exact general fallback (gated; never taken for the fixed bench input).
// Single block, full radix select over all data + dense rewrite. Slow but correct.
__global__ __launch_bounds__(1024) void k_fallback(
    const float* __restrict__ x, float* __restrict__ out,
    const int* __restrict__ kptr, const uint32_t* __restrict__ hdr, uint32_t n) {
  if (hdr[HDR_FLAG] == 0u) return;
  __shared__ uint32_t hist[2048];
  __shared__ uint32_t s_sel, s_rank, s_found, s_eqcnt, s_icut;
  __shared__ uint32_t eq_idx[4096];
  uint32_t tid = threadIdx.x;
  uint32_t K = (uint32_t)kptr[0] * ROWS;
  uint32_t prefix = 0u;
  uint32_t R = K;
  bool zero_thr = (K == 0u);
  for (int lvl = 0; lvl < 3 && !zero_thr; ++lvl) {
    uint32_t shift = (lvl == 0) ? 21u : (lvl == 1 ? 10u : 0u);
    uint32_t nb = (lvl == 2) ? 1024u : 2048u;
    for (uint32_t b = tid; b < nb; b += 1024u) hist[b] = 0u;
    __syncthreads();
    for (uint32_t i = tid; i < n; i += 1024u) {
      float v = x[i];
      uint32_t key = (v > 0.f) ? __float_as_uint(v) : 0u;
      bool valid = (key != 0u);
      if (lvl == 1) valid = valid && ((key >> 21) == prefix);
      if (lvl == 2) valid = valid && ((key >> 10) == prefix);
      if (valid) atomicAdd(&hist[(key >> shift) & (nb - 1u)], 1u);
    }
    __syncthreads();
    if (tid == 0u) {
      uint32_t cum = 0u, sel = 0u, rr = R, found = 0u;
      for (int b = (int)nb - 1; b >= 0; --b) {
        uint32_t c = hist[b];
        if (cum + c >= R) { sel = (uint32_t)b; rr = R - cum; found = 1u; break; }
        cum += c;
      }
      s_sel = sel; s_rank = rr; s_found = found;
    }
    __syncthreads();
    if (s_found == 0u) {
      zero_thr = true;  // fewer than K positives: keep all positives
    } else {
      uint32_t sel = s_sel;
      R = s_rank;
      if (lvl == 0) prefix = sel;
      else if (lvl == 1) prefix = (prefix << 11) | sel;
      else prefix = (prefix << 10) | sel;
    }
    __syncthreads();
  }
  uint32_t thr_key = zero_thr ? 0u : prefix;
  uint32_t icut = 0xFFFFFFFFu;
  if (!zero_thr) {
    uint32_t E = hist[thr_key & 1023u];
    uint32_t T = R;
    if (T < E) {
      if (tid == 0u) { s_eqcnt = 0u; s_icut = 0xFFFFFFFFu; }
      __syncthreads();
      for (uint32_t i = tid; i < n; i += 1024u) {
        float v = x[i];
        if (v > 0.f && __float_as_uint(v) == thr_key) {
          uint32_t p = atomicAdd(&s_eqcnt, 1u);
          if (p < 4096u) eq_idx[p] = i;
        }
      }
      __syncthreads();
      uint32_t ec = s_eqcnt < 4096u ? s_eqcnt : 4096u;
      for (uint32_t e = tid; e < ec; e += 1024u) {
        uint32_t me = eq_idx[e];
        uint32_t rank = 0u;
        for (uint32_t j = 0; j < ec; ++j) rank += (eq_idx[j] < me) ? 1u : 0u;
        if (rank == T - 1u) s_icut = me;
      }
      __syncthreads();
      icut = s_icut;
    }
  }
  for (uint32_t i = tid; i < n; i += 1024u) {
    float v = x[i];
    uint32_t key = (v > 0.f) ? __float_as_uint(v) : 0u;
    bool keep = (key > thr_key) || (key != 0u && key == thr_key && i <= icut);
    out[i] = keep ? v : 0.f;
  }
}

extern "C" void kernel_launch(void* const* d_in, const int* in_sizes, int n_in,
                              void* d_out, int out_size, void* d_ws, size_t ws_size,
                              hipStream_t stream) {
  const float* x = (const float*)d_in[0];
  const int* kptr = (const int*)d_in[1];
  float* out = (float*)d_out;
  uint32_t n = (uint32_t)in_sizes[0];
  uint32_t n4 = n >> 2;

  uint32_t* hdr = (uint32_t*)d_ws;
  uint2* cand = (uint2*)((char*)d_ws + CAND_OFF);
  uint32_t cap = (ws_size > (size_t)CAND_OFF) ? (uint32_t)((ws_size - CAND_OFF) / 8) : 0u;
  // If ws can't hold candidates with margin, force the exact fallback path.
  uint32_t force = (cap < 131072u) ? 1u : 0u;

  k_init<<<1, 64, 0, stream>>>(hdr, force);
  k_compact<<<2048, 256, 0, stream>>>((const float4*)x, (float4*)out, x, out,
                                      cand, hdr, cap, n4, n);
  k_select<<<1, 1024, 0, stream>>>(cand, hdr, kptr, cap);
  k_fallback<<<1, 1024, 0, stream>>>(x, out, kptr, hdr, n);
  k_scatter<<<256, 256, 0, stream>>>(cand, hdr, out, cap);
}

// Round 3
// 569.121 us; speedup vs baseline: 2.3261x; 1.0052x over previous
//
#include <hip/hip_runtime.h>
#include <stdint.h>

// BatchTopK: x (1024, 65536) f32, keep global top k*1024 = 65536 of relu(x), zero rest.
//
// R3: split the dense zero-write out of k_compact. Measured this round:
// write-only rocclr fill runs 6.5 TB/s while the fused read+write compact ran
// ~3.3 TB/s. So: hipMemsetAsync(d_out) [pure write stream] + read-only compact
// [pure read stream]. Select/scatter unchanged (fast since R2).

#define HDR_CURSOR 0
#define HDR_FLAG   1
#define HDR_THR    2
#define HDR_ICUT   3
#define CAND_OFF   4096       // byte offset of candidate buffer in ws
#define LDS_STAGE  2048       // per-block candidate staging (expected ~44/block)
#define ROWS       1024u      // x.shape[0], fixed by the problem
#define SPEC       3.0f       // speculation threshold: count(x>=3.0) ~ 90.6k >= K=65536

__global__ void k_init(uint32_t* hdr, uint32_t force_flag) {
  if (threadIdx.x < 64u) hdr[threadIdx.x] = 0u;
  if (threadIdx.x == 0u) hdr[HDR_FLAG] = force_flag;
}

// Read-only scan of x (2x float4 per thread per iter), append (bits,idx) of
// v>=SPEC into ws via LDS staging (one global cursor bump per block).
__global__ __launch_bounds__(256) void k_compact(
    const float4* __restrict__ x4, const float* __restrict__ x,
    uint2* __restrict__ cand, uint32_t* __restrict__ hdr,
    uint32_t cap, uint32_t n4, uint32_t n) {
  __shared__ uint32_t s_cnt;
  __shared__ uint32_t s_base;
  __shared__ uint2 s_buf[LDS_STAGE];
  if (threadIdx.x == 0u) s_cnt = 0u;
  __syncthreads();

  uint32_t tid = blockIdx.x * blockDim.x + threadIdx.x;
  uint32_t stride = gridDim.x * blockDim.x;
  uint32_t n8 = n4 >> 1;   // pairs of float4
  for (uint32_t i = tid; i < n8; i += stride) {
    float4 a = x4[2u * i];
    float4 b = x4[2u * i + 1u];
    uint32_t gi = i * 8u;
    if (a.x >= SPEC) { uint32_t p = atomicAdd(&s_cnt, 1u); if (p < LDS_STAGE) s_buf[p] = make_uint2(__float_as_uint(a.x), gi); }
    if (a.y >= SPEC) { uint32_t p = atomicAdd(&s_cnt, 1u); if (p < LDS_STAGE) s_buf[p] = make_uint2(__float_as_uint(a.y), gi + 1u); }
    if (a.z >= SPEC) { uint32_t p = atomicAdd(&s_cnt, 1u); if (p < LDS_STAGE) s_buf[p] = make_uint2(__float_as_uint(a.z), gi + 2u); }
    if (a.w >= SPEC) { uint32_t p = atomicAdd(&s_cnt, 1u); if (p < LDS_STAGE) s_buf[p] = make_uint2(__float_as_uint(a.w), gi + 3u); }
    if (b.x >= SPEC) { uint32_t p = atomicAdd(&s_cnt, 1u); if (p < LDS_STAGE) s_buf[p] = make_uint2(__float_as_uint(b.x), gi + 4u); }
    if (b.y >= SPEC) { uint32_t p = atomicAdd(&s_cnt, 1u); if (p < LDS_STAGE) s_buf[p] = make_uint2(__float_as_uint(b.y), gi + 5u); }
    if (b.z >= SPEC) { uint32_t p = atomicAdd(&s_cnt, 1u); if (p < LDS_STAGE) s_buf[p] = make_uint2(__float_as_uint(b.z), gi + 6u); }
    if (b.w >= SPEC) { uint32_t p = atomicAdd(&s_cnt, 1u); if (p < LDS_STAGE) s_buf[p] = make_uint2(__float_as_uint(b.w), gi + 7u); }
  }
  // tail: elements beyond n8*8 (none for the fixed input, correct anyway)
  uint32_t tail0 = n8 * 8u;
  if (blockIdx.x == 0u && threadIdx.x < (n - tail0)) {
    uint32_t gi = tail0 + threadIdx.x;
    float v = x[gi];
    if (v >= SPEC) { uint32_t p = atomicAdd(&s_cnt, 1u); if (p < LDS_STAGE) s_buf[p] = make_uint2(__float_as_uint(v), gi); }
  }
  __syncthreads();
  uint32_t cnt = s_cnt;
  if (cnt == 0u) return;
  uint32_t wcnt = cnt < (uint32_t)LDS_STAGE ? cnt : (uint32_t)LDS_STAGE;
  if (threadIdx.x == 0u) {
    s_base = atomicAdd(&hdr[HDR_CURSOR], cnt);  // true total (dropped entries flagged)
    if (cnt > (uint32_t)LDS_STAGE) atomicOr(&hdr[HDR_FLAG], 1u);
  }
  __syncthreads();
  uint32_t base = s_base;
  for (uint32_t j = threadIdx.x; j < wcnt; j += blockDim.x) {
    uint32_t g = base + j;
    if (g < cap) cand[g] = s_buf[j];
  }
  if (threadIdx.x == 0u && base + wcnt > cap) atomicOr(&hdr[HDR_FLAG], 1u);
}

// Single block: exact K-th largest among candidates via 3-level radix (11/11/10 bits).
// Plain LDS atomics + wave-parallel suffix scan. Stable tie cut via T-th smallest index.
__global__ __launch_bounds__(1024) void k_select(
    const uint2* __restrict__ cand, uint32_t* __restrict__ hdr,
    const int* __restrict__ kptr, uint32_t cap) {
  __shared__ uint32_t hist[2048];
  __shared__ uint32_t s_sel, s_rank, s_eqcnt, s_icut;
  __shared__ uint32_t eq_idx[4096];
  uint32_t tid = threadIdx.x;
  uint32_t K = (uint32_t)kptr[0] * ROWS;
  uint32_t M = hdr[HDR_CURSOR];
  if (hdr[HDR_FLAG] != 0u || M > cap || M < K) {
    if (tid == 0u) hdr[HDR_FLAG] = 1u;
    return;
  }
  if (K == 0u) {  // keep nothing; no candidate key can be 0xFFFFFFFF (all >= 3.0)
    if (tid == 0u) { hdr[HDR_THR] = 0xFFFFFFFFu; hdr[HDR_ICUT] = 0xFFFFFFFFu; }
    return;
  }
  const uint4* __restrict__ cand4 = (const uint4*)cand;
  uint32_t M2 = M >> 1;
  uint32_t R = K;        // 1-indexed rank within current subset
  uint32_t prefix = 0u;  // accumulated high bits of the threshold key
  for (int lvl = 0; lvl < 3; ++lvl) {
    uint32_t shift = (lvl == 0) ? 21u : (lvl == 1 ? 10u : 0u);
    uint32_t nb = (lvl == 2) ? 1024u : 2048u;
    for (uint32_t b = tid; b < nb; b += 1024u) hist[b] = 0u;
    __syncthreads();
    for (uint32_t j = tid; j < M2; j += 1024u) {
      uint4 c = cand4[j];                 // two candidates: keys c.x and c.z
      uint32_t k0 = c.x, k1 = c.z;
      bool v0 = true, v1 = true;
      if (lvl == 1) { v0 = ((k0 >> 21) == prefix); v1 = ((k1 >> 21) == prefix); }
      if (lvl == 2) { v0 = ((k0 >> 10) == prefix); v1 = ((k1 >> 10) == prefix); }
      if (v0) atomicAdd(&hist[(k0 >> shift) & (nb - 1u)], 1u);
      if (v1) atomicAdd(&hist[(k1 >> shift) & (nb - 1u)], 1u);
    }
    if (tid == 0u && (M & 1u)) {
      uint32_t key = cand[M - 1u].x;
      bool v = true;
      if (lvl == 1) v = ((key >> 21) == prefix);
      if (lvl == 2) v = ((key >> 10) == prefix);
      if (v) atomicAdd(&hist[(key >> shift) & (nb - 1u)], 1u);
    }
    __syncthreads();
    // wave 0: parallel suffix scan over nb bins to find the bin holding rank R
    if (tid < 64u) {
      uint32_t seg = nb >> 6;            // bins per lane: 32 or 16
      uint32_t base = tid * seg;
      uint32_t lanesum = 0u;
      for (uint32_t j = 0; j < seg; ++j) lanesum += hist[base + j];
      uint32_t s = lanesum;              // inclusive suffix scan across lanes
      for (int d = 1; d < 64; d <<= 1) {
        uint32_t v = (uint32_t)__shfl_down((int)s, d, 64);
        if ((int)tid + d < 64) s += v;
      }
      uint32_t above = s - lanesum;      // total count in lanes > tid
      if (above < R && above + lanesum >= R) {   // exactly one lane
        uint32_t r = R - above;
        uint32_t cum = 0u;
        for (int j = (int)seg - 1; j >= 0; --j) {
          uint32_t c = hist[base + (uint32_t)j];
          if (cum + c >= r) { s_sel = base + (uint32_t)j; s_rank = r - cum; break; }
          cum += c;
        }
      }
    }
    __syncthreads();
    uint32_t sel = s_sel;
    R = s_rank;
    if (lvl == 0) prefix = sel;
    else if (lvl == 1) prefix = (prefix << 11) | sel;
    else prefix = (prefix << 10) | sel;
  }
  uint32_t thr_key = prefix;
  uint32_t E = hist[thr_key & 1023u];  // count of keys == thr among candidates
  uint32_t T = R;                      // how many equals to keep (lowest indices)
  uint32_t icut = 0xFFFFFFFFu;
  if (T < E) {
    if (tid == 0u) { s_eqcnt = 0u; s_icut = 0xFFFFFFFFu; }
    __syncthreads();
    for (uint32_t i = tid; i < M; i += 1024u) {
      uint2 c = cand[i];
      if (c.x == thr_key) { uint32_t p = atomicAdd(&s_eqcnt, 1u); if (p < 4096u) eq_idx[p] = c.y; }
    }
    __syncthreads();
    if (s_eqcnt > 4096u) {             // can't rank ties exactly here -> exact fallback
      if (tid == 0u) hdr[HDR_FLAG] = 1u;
      return;
    }
    uint32_t ec = s_eqcnt;
    for (uint32_t e = tid; e < ec; e += 1024u) {
      uint32_t me = eq_idx[e];
      uint32_t rank = 0u;
      for (uint32_t j = 0; j < ec; ++j) rank += (eq_idx[j] < me) ? 1u : 0u;
      if (rank == T - 1u) s_icut = me;   // T-th smallest equal index
    }
    __syncthreads();
    icut = s_icut;
  }
  if (tid == 0u) { hdr[HDR_THR] = thr_key; hdr[HDR_ICUT] = icut; }
}

// Sparse scatter of kept candidates into the pre-zeroed (memset) output.
__global__ __launch_bounds__(256) void k_scatter(
    const uint2* __restrict__ cand, const uint32_t* __restrict__ hdr,
    float* __restrict__ out, uint32_t cap) {
  if (hdr[HDR_FLAG] != 0u) return;
  uint32_t M = hdr[HDR_CURSOR]; if (M > cap) M = cap;
  uint32_t thr = hdr[HDR_THR], icut = hdr[HDR_ICUT];
  uint32_t stride = gridDim.x * blockDim.x;
  for (uint32_t i = blockIdx.x * blockDim.x + threadIdx.x; i < M; i += stride) {
    uint2 c = cand[i];
    if (c.x > thr || (c.x == thr && c.y <= icut)) out[c.y] = __uint_as_float(c.x);
  }
}

// Exact general fallback (gated; never taken for the fixed bench input).
// Single block, full radix select over all data + dense rewrite. Slow but correct.
__global__ __launch_bounds__(1024) void k_fallback(
    const float* __restrict__ x, float* __restrict__ out,
    const int* __restrict__ kptr, const uint32_t* __restrict__ hdr, uint32_t n) {
  if (hdr[HDR_FLAG] == 0u) return;
  __shared__ uint32_t hist[2048];
  __shared__ uint32_t s_sel, s_rank, s_found, s_eqcnt, s_icut;
  __shared__ uint32_t eq_idx[4096];
  uint32_t tid = threadIdx.x;
  uint32_t K = (uint32_t)kptr[0] * ROWS;
  uint32_t prefix = 0u;
  uint32_t R = K;
  bool zero_thr = (K == 0u);
  for (int lvl = 0; lvl < 3 && !zero_thr; ++lvl) {
    uint32_t shift = (lvl == 0) ? 21u : (lvl == 1 ? 10u : 0u);
    uint32_t nb = (lvl == 2) ? 1024u : 2048u;
    for (uint32_t b = tid; b < nb; b += 1024u) hist[b] = 0u;
    __syncthreads();
    for (uint32_t i = tid; i < n; i += 1024u) {
      float v = x[i];
      uint32_t key = (v > 0.f) ? __float_as_uint(v) : 0u;
      bool valid = (key != 0u);
      if (lvl == 1) valid = valid && ((key >> 21) == prefix);
      if (lvl == 2) valid = valid && ((key >> 10) == prefix);
      if (valid) atomicAdd(&hist[(key >> shift) & (nb - 1u)], 1u);
    }
    __syncthreads();
    if (tid == 0u) {
      uint32_t cum = 0u, sel = 0u, rr = R, found = 0u;
      for (int b = (int)nb - 1; b >= 0; --b) {
        uint32_t c = hist[b];
        if (cum + c >= R) { sel = (uint32_t)b; rr = R - cum; found = 1u; break; }
        cum += c;
      }
      s_sel = sel; s_rank = rr; s_found = found;
    }
    __syncthreads();
    if (s_found == 0u) {
      zero_thr = true;  // fewer than K positives: keep all positives
    } else {
      uint32_t sel = s_sel;
      R = s_rank;
      if (lvl == 0) prefix = sel;
      else if (lvl == 1) prefix = (prefix << 11) | sel;
      else prefix = (prefix << 10) | sel;
    }
    __syncthreads();
  }
  uint32_t thr_key = zero_thr ? 0u : prefix;
  uint32_t icut = 0xFFFFFFFFu;
  if (!zero_thr) {
    uint32_t E = hist[thr_key & 1023u];
    uint32_t T = R;
    if (T < E) {
      if (tid == 0u) { s_eqcnt = 0u; s_icut = 0xFFFFFFFFu; }
      __syncthreads();
      for (uint32_t i = tid; i < n; i += 1024u) {
        float v = x[i];
        if (v > 0.f && __float_as_uint(v) == thr_key) {
          uint32_t p = atomicAdd(&s_eqcnt, 1u);
          if (p < 4096u) eq_idx[p] = i;
        }
      }
      __syncthreads();
      uint32_t ec = s_eqcnt < 4096u ? s_eqcnt : 4096u;
      for (uint32_t e = tid; e < ec; e += 1024u) {
        uint32_t me = eq_idx[e];
        uint32_t rank = 0u;
        for (uint32_t j = 0; j < ec; ++j) rank += (eq_idx[j] < me) ? 1u : 0u;
        if (rank == T - 1u) s_icut = me;
      }
      __syncthreads();
      icut = s_icut;
    }
  }
  for (uint32_t i = tid; i < n; i += 1024u) {
    float v = x[i];
    uint32_t key = (v > 0.f) ? __float_as_uint(v) : 0u;
    bool keep = (key > thr_key) || (key != 0u && key == thr_key && i <= icut);
    out[i] = keep ? v : 0.f;
  }
}

extern "C" void kernel_launch(void* const* d_in, const int* in_sizes, int n_in,
                              void* d_out, int out_size, void* d_ws, size_t ws_size,
                              hipStream_t stream) {
  const float* x = (const float*)d_in[0];
  const int* kptr = (const int*)d_in[1];
  float* out = (float*)d_out;
  uint32_t n = (uint32_t)in_sizes[0];
  uint32_t n4 = n >> 2;

  uint32_t* hdr = (uint32_t*)d_ws;
  uint2* cand = (uint2*)((char*)d_ws + CAND_OFF);
  uint32_t cap = (ws_size > (size_t)CAND_OFF) ? (uint32_t)((ws_size - CAND_OFF) / 8) : 0u;
  // If ws can't hold candidates with margin, force the exact fallback path.
  uint32_t force = (cap < 131072u) ? 1u : 0u;

  k_init<<<1, 64, 0, stream>>>(hdr, force);
  // Dense zero of d_out as a pure write stream (rocclr fill measured 6.5 TB/s).
  hipMemsetAsync(d_out, 0, (size_t)out_size * sizeof(float), stream);
  // Pure read stream: compact candidates.
  k_compact<<<2048, 256, 0, stream>>>((const float4*)x, x, cand, hdr, cap, n4, n);
  k_select<<<1, 1024, 0, stream>>>(cand, hdr, kptr, cap);
  k_fallback<<<1, 1024, 0, stream>>>(x, out, kptr, hdr, n);
  k_scatter<<<256, 256, 0, stream>>>(cand, hdr, out, cap);
}

// Round 4
// 563.134 us; speedup vs baseline: 2.3508x; 1.0106x over previous
//
#include <hip/hip_runtime.h>
#include <stdint.h>

// BatchTopK: x (1024, 65536) f32, keep global top k*1024 = 65536 of relu(x), zero rest.
//
// R4: single fused dense pass — even-parity blocks zero d_out (pure write
// stream), odd-parity blocks scan x for candidates (pure read stream),
// CONCURRENTLY (m13: 6.29 TB/s is read+write concurrent; serializing the
// streams as R3 did forfeits that). Wave-uniform ballot skip in the scan.

#define HDR_CURSOR 0
#define HDR_FLAG   1
#define HDR_THR    2
#define HDR_ICUT   3
#define CAND_OFF   4096       // byte offset of candidate buffer in ws
#define LDS_STAGE  2048       // per-block candidate staging (expected ~44/block)
#define ROWS       1024u      // x.shape[0], fixed by the problem
#define SPEC       3.0f       // speculation threshold: count(x>=3.0) ~ 90.6k >= K=65536

__global__ void k_init(uint32_t* hdr, uint32_t force_flag) {
  if (threadIdx.x < 64u) hdr[threadIdx.x] = 0u;
  if (threadIdx.x == 0u) hdr[HDR_FLAG] = force_flag;
}

// Fused: even blocks zero out[], odd blocks scan x[] and append candidates.
__global__ __launch_bounds__(256) void k_zero_scan(
    float4* __restrict__ out4, float* __restrict__ out,
    const float4* __restrict__ x4, const float* __restrict__ x,
    uint2* __restrict__ cand, uint32_t* __restrict__ hdr,
    uint32_t cap, uint32_t n4, uint32_t n, uint32_t half) {
  uint32_t role = blockIdx.x & 1u;   // 0 = zero-writer, 1 = scanner
  uint32_t bid  = blockIdx.x >> 1;   // block index within role
  uint32_t stride = half * 256u;
  uint32_t tail0 = n4 * 4u;

  if (role == 0u) {
    const float4 z = make_float4(0.f, 0.f, 0.f, 0.f);
    for (uint32_t i = bid * 256u + threadIdx.x; i < n4; i += stride)
      out4[i] = z;
    if (bid == 0u && threadIdx.x < (n - tail0))
      out[tail0 + threadIdx.x] = 0.f;
    return;
  }

  __shared__ uint32_t s_cnt;
  __shared__ uint32_t s_base;
  __shared__ uint2 s_buf[LDS_STAGE];
  if (threadIdx.x == 0u) s_cnt = 0u;
  __syncthreads();

  for (uint32_t i = bid * 256u + threadIdx.x; i < n4; i += stride) {
    float4 a = x4[i];
    bool has = (a.x >= SPEC) || (a.y >= SPEC) || (a.z >= SPEC) || (a.w >= SPEC);
    if (__ballot(has ? 1 : 0)) {        // wave-uniform: 71% of iterations skip
      uint32_t gi = i * 4u;
      if (a.x >= SPEC) { uint32_t p = atomicAdd(&s_cnt, 1u); if (p < LDS_STAGE) s_buf[p] = make_uint2(__float_as_uint(a.x), gi); }
      if (a.y >= SPEC) { uint32_t p = atomicAdd(&s_cnt, 1u); if (p < LDS_STAGE) s_buf[p] = make_uint2(__float_as_uint(a.y), gi + 1u); }
      if (a.z >= SPEC) { uint32_t p = atomicAdd(&s_cnt, 1u); if (p < LDS_STAGE) s_buf[p] = make_uint2(__float_as_uint(a.z), gi + 2u); }
      if (a.w >= SPEC) { uint32_t p = atomicAdd(&s_cnt, 1u); if (p < LDS_STAGE) s_buf[p] = make_uint2(__float_as_uint(a.w), gi + 3u); }
    }
  }
  if (bid == 0u && threadIdx.x < (n - tail0)) {
    uint32_t gi = tail0 + threadIdx.x;
    float v = x[gi];
    if (v >= SPEC) { uint32_t p = atomicAdd(&s_cnt, 1u); if (p < LDS_STAGE) s_buf[p] = make_uint2(__float_as_uint(v), gi); }
  }
  __syncthreads();
  uint32_t cnt = s_cnt;
  if (cnt == 0u) return;
  uint32_t wcnt = cnt < (uint32_t)LDS_STAGE ? cnt : (uint32_t)LDS_STAGE;
  if (threadIdx.x == 0u) {
    s_base = atomicAdd(&hdr[HDR_CURSOR], cnt);  // true total (drops flagged)
    if (cnt > (uint32_t)LDS_STAGE) atomicOr(&hdr[HDR_FLAG], 1u);
  }
  __syncthreads();
  uint32_t base = s_base;
  for (uint32_t j = threadIdx.x; j < wcnt; j += blockDim.x) {
    uint32_t g = base + j;
    if (g < cap) cand[g] = s_buf[j];
  }
  if (threadIdx.x == 0u && base + wcnt > cap) atomicOr(&hdr[HDR_FLAG], 1u);
}

// Single block: exact K-th largest among candidates via 3-level radix (11/11/10 bits).
// Plain LDS atomics + wave-parallel suffix scan. Stable tie cut via T-th smallest index.
__global__ __launch_bounds__(1024) void k_select(
    const uint2* __restrict__ cand, uint32_t* __restrict__ hdr,
    const int* __restrict__ kptr, uint32_t cap) {
  __shared__ uint32_t hist[2048];
  __shared__ uint32_t s_sel, s_rank, s_eqcnt, s_icut;
  __shared__ uint32_t eq_idx[4096];
  uint32_t tid = threadIdx.x;
  uint32_t K = (uint32_t)kptr[0] * ROWS;
  uint32_t M = hdr[HDR_CURSOR];
  if (hdr[HDR_FLAG] != 0u || M > cap || M < K) {
    if (tid == 0u) hdr[HDR_FLAG] = 1u;
    return;
  }
  if (K == 0u) {  // keep nothing; no candidate key can be 0xFFFFFFFF (all >= 3.0)
    if (tid == 0u) { hdr[HDR_THR] = 0xFFFFFFFFu; hdr[HDR_ICUT] = 0xFFFFFFFFu; }
    return;
  }
  const uint4* __restrict__ cand4 = (const uint4*)cand;
  uint32_t M2 = M >> 1;
  uint32_t R = K;        // 1-indexed rank within current subset
  uint32_t prefix = 0u;  // accumulated high bits of the threshold key
  for (int lvl = 0; lvl < 3; ++lvl) {
    uint32_t shift = (lvl == 0) ? 21u : (lvl == 1 ? 10u : 0u);
    uint32_t nb = (lvl == 2) ? 1024u : 2048u;
    for (uint32_t b = tid; b < nb; b += 1024u) hist[b] = 0u;
    __syncthreads();
    for (uint32_t j = tid; j < M2; j += 1024u) {
      uint4 c = cand4[j];                 // two candidates: keys c.x and c.z
      uint32_t k0 = c.x, k1 = c.z;
      bool v0 = true, v1 = true;
      if (lvl == 1) { v0 = ((k0 >> 21) == prefix); v1 = ((k1 >> 21) == prefix); }
      if (lvl == 2) { v0 = ((k0 >> 10) == prefix); v1 = ((k1 >> 10) == prefix); }
      if (v0) atomicAdd(&hist[(k0 >> shift) & (nb - 1u)], 1u);
      if (v1) atomicAdd(&hist[(k1 >> shift) & (nb - 1u)], 1u);
    }
    if (tid == 0u && (M & 1u)) {
      uint32_t key = cand[M - 1u].x;
      bool v = true;
      if (lvl == 1) v = ((key >> 21) == prefix);
      if (lvl == 2) v = ((key >> 10) == prefix);
      if (v) atomicAdd(&hist[(key >> shift) & (nb - 1u)], 1u);
    }
    __syncthreads();
    // wave 0: parallel suffix scan over nb bins to find the bin holding rank R
    if (tid < 64u) {
      uint32_t seg = nb >> 6;            // bins per lane: 32 or 16
      uint32_t base = tid * seg;
      uint32_t lanesum = 0u;
      for (uint32_t j = 0; j < seg; ++j) lanesum += hist[base + j];
      uint32_t s = lanesum;              // inclusive suffix scan across lanes
      for (int d = 1; d < 64; d <<= 1) {
        uint32_t v = (uint32_t)__shfl_down((int)s, d, 64);
        if ((int)tid + d < 64) s += v;
      }
      uint32_t above = s - lanesum;      // total count in lanes > tid
      if (above < R && above + lanesum >= R) {   // exactly one lane
        uint32_t r = R - above;
        uint32_t cum = 0u;
        for (int j = (int)seg - 1; j >= 0; --j) {
          uint32_t c = hist[base + (uint32_t)j];
          if (cum + c >= r) { s_sel = base + (uint32_t)j; s_rank = r - cum; break; }
          cum += c;
        }
      }
    }
    __syncthreads();
    uint32_t sel = s_sel;
    R = s_rank;
    if (lvl == 0) prefix = sel;
    else if (lvl == 1) prefix = (prefix << 11) | sel;
    else prefix = (prefix << 10) | sel;
  }
  uint32_t thr_key = prefix;
  uint32_t E = hist[thr_key & 1023u];  // count of keys == thr among candidates
  uint32_t T = R;                      // how many equals to keep (lowest indices)
  uint32_t icut = 0xFFFFFFFFu;
  if (T < E) {
    if (tid == 0u) { s_eqcnt = 0u; s_icut = 0xFFFFFFFFu; }
    __syncthreads();
    for (uint32_t i = tid; i < M; i += 1024u) {
      uint2 c = cand[i];
      if (c.x == thr_key) { uint32_t p = atomicAdd(&s_eqcnt, 1u); if (p < 4096u) eq_idx[p] = c.y; }
    }
    __syncthreads();
    if (s_eqcnt > 4096u) {             // can't rank ties exactly here -> exact fallback
      if (tid == 0u) hdr[HDR_FLAG] = 1u;
      return;
    }
    uint32_t ec = s_eqcnt;
    for (uint32_t e = tid; e < ec; e += 1024u) {
      uint32_t me = eq_idx[e];
      uint32_t rank = 0u;
      for (uint32_t j = 0; j < ec; ++j) rank += (eq_idx[j] < me) ? 1u : 0u;
      if (rank == T - 1u) s_icut = me;   // T-th smallest equal index
    }
    __syncthreads();
    icut = s_icut;
  }
  if (tid == 0u) { hdr[HDR_THR] = thr_key; hdr[HDR_ICUT] = icut; }
}

// Sparse scatter of kept candidates into the zeroed output.
__global__ __launch_bounds__(256) void k_scatter(
    const uint2* __restrict__ cand, const uint32_t* __restrict__ hdr,
    float* __restrict__ out, uint32_t cap) {
  if (hdr[HDR_FLAG] != 0u) return;
  uint32_t M = hdr[HDR_CURSOR]; if (M > cap) M = cap;
  uint32_t thr = hdr[HDR_THR], icut = hdr[HDR_ICUT];
  uint32_t stride = gridDim.x * blockDim.x;
  for (uint32_t i = blockIdx.x * blockDim.x + threadIdx.x; i < M; i += stride) {
    uint2 c = cand[i];
    if (c.x > thr || (c.x == thr && c.y <= icut)) out[c.y] = __uint_as_float(c.x);
  }
}

// Exact general fallback (gated; never taken for the fixed bench input).
// Single block, full radix select over all data + dense rewrite. Slow but correct.
__global__ __launch_bounds__(1024) void k_fallback(
    const float* __restrict__ x, float* __restrict__ out,
    const int* __restrict__ kptr, const uint32_t* __restrict__ hdr, uint32_t n) {
  if (hdr[HDR_FLAG] == 0u) return;
  __shared__ uint32_t hist[2048];
  __shared__ uint32_t s_sel, s_rank, s_found, s_eqcnt, s_icut;
  __shared__ uint32_t eq_idx[4096];
  uint32_t tid = threadIdx.x;
  uint32_t K = (uint32_t)kptr[0] * ROWS;
  uint32_t prefix = 0u;
  uint32_t R = K;
  bool zero_thr = (K == 0u);
  for (int lvl = 0; lvl < 3 && !zero_thr; ++lvl) {
    uint32_t shift = (lvl == 0) ? 21u : (lvl == 1 ? 10u : 0u);
    uint32_t nb = (lvl == 2) ? 1024u : 2048u;
    for (uint32_t b = tid; b < nb; b += 1024u) hist[b] = 0u;
    __syncthreads();
    for (uint32_t i = tid; i < n; i += 1024u) {
      float v = x[i];
      uint32_t key = (v > 0.f) ? __float_as_uint(v) : 0u;
      bool valid = (key != 0u);
      if (lvl == 1) valid = valid && ((key >> 21) == prefix);
      if (lvl == 2) valid = valid && ((key >> 10) == prefix);
      if (valid) atomicAdd(&hist[(key >> shift) & (nb - 1u)], 1u);
    }
    __syncthreads();
    if (tid == 0u) {
      uint32_t cum = 0u, sel = 0u, rr = R, found = 0u;
      for (int b = (int)nb - 1; b >= 0; --b) {
        uint32_t c = hist[b];
        if (cum + c >= R) { sel = (uint32_t)b; rr = R - cum; found = 1u; break; }
        cum += c;
      }
      s_sel = sel; s_rank = rr; s_found = found;
    }
    __syncthreads();
    if (s_found == 0u) {
      zero_thr = true;  // fewer than K positives: keep all positives
    } else {
      uint32_t sel = s_sel;
      R = s_rank;
      if (lvl == 0) prefix = sel;
      else if (lvl == 1) prefix = (prefix << 11) | sel;
      else prefix = (prefix << 10) | sel;
    }
    __syncthreads();
  }
  uint32_t thr_key = zero_thr ? 0u : prefix;
  uint32_t icut = 0xFFFFFFFFu;
  if (!zero_thr) {
    uint32_t E = hist[thr_key & 1023u];
    uint32_t T = R;
    if (T < E) {
      if (tid == 0u) { s_eqcnt = 0u; s_icut = 0xFFFFFFFFu; }
      __syncthreads();
      for (uint32_t i = tid; i < n; i += 1024u) {
        float v = x[i];
        if (v > 0.f && __float_as_uint(v) == thr_key) {
          uint32_t p = atomicAdd(&s_eqcnt, 1u);
          if (p < 4096u) eq_idx[p] = i;
        }
      }
      __syncthreads();
      uint32_t ec = s_eqcnt < 4096u ? s_eqcnt : 4096u;
      for (uint32_t e = tid; e < ec; e += 1024u) {
        uint32_t me = eq_idx[e];
        uint32_t rank = 0u;
        for (uint32_t j = 0; j < ec; ++j) rank += (eq_idx[j] < me) ? 1u : 0u;
        if (rank == T - 1u) s_icut = me;
      }
      __syncthreads();
      icut = s_icut;
    }
  }
  for (uint32_t i = tid; i < n; i += 1024u) {
    float v = x[i];
    uint32_t key = (v > 0.f) ? __float_as_uint(v) : 0u;
    bool keep = (key > thr_key) || (key != 0u && key == thr_key && i <= icut);
    out[i] = keep ? v : 0.f;
  }
}

extern "C" void kernel_launch(void* const* d_in, const int* in_sizes, int n_in,
                              void* d_out, int out_size, void* d_ws, size_t ws_size,
                              hipStream_t stream) {
  const float* x = (const float*)d_in[0];
  const int* kptr = (const int*)d_in[1];
  float* out = (float*)d_out;
  uint32_t n = (uint32_t)in_sizes[0];
  uint32_t n4 = n >> 2;

  uint32_t* hdr = (uint32_t*)d_ws;
  uint2* cand = (uint2*)((char*)d_ws + CAND_OFF);
  uint32_t cap = (ws_size > (size_t)CAND_OFF) ? (uint32_t)((ws_size - CAND_OFF) / 8) : 0u;
  // If ws can't hold candidates with margin, force the exact fallback path.
  uint32_t force = (cap < 131072u) ? 1u : 0u;

  const uint32_t HALF = 2048u;  // blocks per role; grid = 2*HALF, parity-interleaved
  k_init<<<1, 64, 0, stream>>>(hdr, force);
  k_zero_scan<<<2u * HALF, 256, 0, stream>>>((float4*)out, out, (const float4*)x, x,
                                             cand, hdr, cap, n4, n, HALF);
  k_select<<<1, 1024, 0, stream>>>(cand, hdr, kptr, cap);
  k_fallback<<<1, 1024, 0, stream>>>(x, out, kptr, hdr, n);
  k_scatter<<<256, 256, 0, stream>>>(cand, hdr, out, cap);
}

// Round 5
// 496.609 us; speedup vs baseline: 2.6657x; 1.1340x over previous
//
#include <hip/hip_runtime.h>
#include <stdint.h>

// BatchTopK: x (1024, 65536) f32, keep global top k*1024 = 65536 of relu(x), zero rest.
//
// R5: kill k_select's hidden cost. R2-R4's level-0 radix binned by top 11 bits,
// but all candidates lie in [3.0, 5.7] -> ~6 distinct bins -> 90k same-word LDS
// atomics serialized on one CU (~100us). Now: linear histogram of
// (key - bits(3.0)) >> 12 (2048 bins, ~0.001 value width, hottest bin ~300)
// built grid-wide in the scan kernel's flush loop; select = suffix scan +
// one candidate pass collecting the target bucket + exact composite rank.

#define HDR_CURSOR 0
#define HDR_FLAG   1
#define HDR_THR    2
#define HDR_ICUT   3
#define HIST_OFF   4096       // uint32 hist[2048] at ws+4096
#define CAND_OFF   16384      // candidate buffer
#define NBINS      2048u
#define BUCKET_CAP 6144u
#define LDS_STAGE  2048       // per-block candidate staging (expected ~44/block)
#define ROWS       1024u      // x.shape[0], fixed by the problem
#define SPEC       3.0f       // count(x>=3.0) ~ 90.6k >= K=65536
#define BASE_BITS  0x40400000u  // __float_as_uint(3.0f)

__device__ __forceinline__ uint32_t bin_of(uint32_t key) {
  uint32_t off = key - BASE_BITS;        // key >= BASE_BITS guaranteed by SPEC filter
  uint32_t b = off >> 12;
  return b < NBINS ? b : (NBINS - 1u);
}

__global__ void k_init(uint32_t* hdr, uint32_t* ghist, uint32_t force_flag) {
  for (uint32_t i = threadIdx.x; i < 64u + NBINS; i += 256u) {
    if (i < 64u) hdr[i] = 0u;
    else ghist[i - 64u] = 0u;
  }
  if (threadIdx.x == 0u) hdr[HDR_FLAG] = force_flag;
}

// Fused: even blocks zero out[], odd blocks scan x[], append candidates, and
// accumulate the global linear histogram during the flush.
__global__ __launch_bounds__(256) void k_zero_scan(
    float4* __restrict__ out4, float* __restrict__ out,
    const float4* __restrict__ x4, const float* __restrict__ x,
    uint2* __restrict__ cand, uint32_t* __restrict__ hdr,
    uint32_t* __restrict__ ghist,
    uint32_t cap, uint32_t n4, uint32_t n, uint32_t half) {
  uint32_t role = blockIdx.x & 1u;   // 0 = zero-writer, 1 = scanner
  uint32_t bid  = blockIdx.x >> 1;   // block index within role
  uint32_t stride = half * 256u;
  uint32_t tail0 = n4 * 4u;

  if (role == 0u) {
    const float4 z = make_float4(0.f, 0.f, 0.f, 0.f);
    for (uint32_t i = bid * 256u + threadIdx.x; i < n4; i += stride)
      out4[i] = z;
    if (bid == 0u && threadIdx.x < (n - tail0))
      out[tail0 + threadIdx.x] = 0.f;
    return;
  }

  __shared__ uint32_t s_cnt;
  __shared__ uint32_t s_base;
  __shared__ uint2 s_buf[LDS_STAGE];
  if (threadIdx.x == 0u) s_cnt = 0u;
  __syncthreads();

  for (uint32_t i = bid * 256u + threadIdx.x; i < n4; i += stride) {
    float4 a = x4[i];
    bool has = (a.x >= SPEC) || (a.y >= SPEC) || (a.z >= SPEC) || (a.w >= SPEC);
    if (__ballot(has ? 1 : 0)) {        // wave-uniform: ~71% of iterations skip
      uint32_t gi = i * 4u;
      if (a.x >= SPEC) { uint32_t p = atomicAdd(&s_cnt, 1u); if (p < LDS_STAGE) s_buf[p] = make_uint2(__float_as_uint(a.x), gi); }
      if (a.y >= SPEC) { uint32_t p = atomicAdd(&s_cnt, 1u); if (p < LDS_STAGE) s_buf[p] = make_uint2(__float_as_uint(a.y), gi + 1u); }
      if (a.z >= SPEC) { uint32_t p = atomicAdd(&s_cnt, 1u); if (p < LDS_STAGE) s_buf[p] = make_uint2(__float_as_uint(a.z), gi + 2u); }
      if (a.w >= SPEC) { uint32_t p = atomicAdd(&s_cnt, 1u); if (p < LDS_STAGE) s_buf[p] = make_uint2(__float_as_uint(a.w), gi + 3u); }
    }
  }
  if (bid == 0u && threadIdx.x < (n - tail0)) {
    uint32_t gi = tail0 + threadIdx.x;
    float v = x[gi];
    if (v >= SPEC) { uint32_t p = atomicAdd(&s_cnt, 1u); if (p < LDS_STAGE) s_buf[p] = make_uint2(__float_as_uint(v), gi); }
  }
  __syncthreads();
  uint32_t cnt = s_cnt;
  if (cnt == 0u) return;
  uint32_t wcnt = cnt < (uint32_t)LDS_STAGE ? cnt : (uint32_t)LDS_STAGE;
  if (threadIdx.x == 0u) {
    s_base = atomicAdd(&hdr[HDR_CURSOR], cnt);  // true total (drops flagged)
    if (cnt > (uint32_t)LDS_STAGE) atomicOr(&hdr[HDR_FLAG], 1u);
  }
  __syncthreads();
  uint32_t base = s_base;
  for (uint32_t j = threadIdx.x; j < wcnt; j += blockDim.x) {
    uint32_t g = base + j;
    if (g < cap) {
      uint2 c = s_buf[j];
      cand[g] = c;
      atomicAdd(&ghist[bin_of(c.x)], 1u);   // ~44/block, spread over 2048 words
    }
  }
  if (threadIdx.x == 0u && base + wcnt > cap) atomicOr(&hdr[HDR_FLAG], 1u);
}

// Single block: pick rank-K bin from the prebuilt 2048-bin linear histogram,
// collect that bin's candidates (expected ~220), exact composite-rank select.
__global__ __launch_bounds__(1024) void k_select(
    const uint2* __restrict__ cand, uint32_t* __restrict__ hdr,
    const uint32_t* __restrict__ ghist,
    const int* __restrict__ kptr, uint32_t cap) {
  __shared__ uint32_t h[NBINS];
  __shared__ uint32_t s_sel, s_rank, s_bcnt;
  __shared__ uint2 bkt[BUCKET_CAP];
  uint32_t tid = threadIdx.x;
  uint32_t K = (uint32_t)kptr[0] * ROWS;
  uint32_t M = hdr[HDR_CURSOR];
  if (hdr[HDR_FLAG] != 0u || M > cap || M < K) {
    if (tid == 0u) hdr[HDR_FLAG] = 1u;
    return;
  }
  if (K == 0u) {  // keep nothing; candidate keys are finite positive floats < 0xFFFFFFFF
    if (tid == 0u) { hdr[HDR_THR] = 0xFFFFFFFFu; hdr[HDR_ICUT] = 0xFFFFFFFFu; }
    return;
  }
  h[tid] = ghist[tid];
  h[tid + 1024u] = ghist[tid + 1024u];
  if (tid == 0u) s_bcnt = 0u;
  __syncthreads();
  // wave 0: suffix scan over 2048 bins to find the bin holding rank K
  if (tid < 64u) {
    uint32_t seg = NBINS >> 6;           // 32 bins per lane
    uint32_t base = tid * seg;
    uint32_t lanesum = 0u;
    for (uint32_t j = 0; j < seg; ++j) lanesum += h[base + j];
    uint32_t s = lanesum;                // inclusive suffix scan across lanes
    for (int d = 1; d < 64; d <<= 1) {
      uint32_t v = (uint32_t)__shfl_down((int)s, d, 64);
      if ((int)tid + d < 64) s += v;
    }
    uint32_t above = s - lanesum;        // total count in lanes > tid
    if (above < K && above + lanesum >= K) {   // exactly one lane matches
      uint32_t r = K - above;
      uint32_t cum = 0u;
      for (int j = (int)seg - 1; j >= 0; --j) {
        uint32_t c = h[base + (uint32_t)j];
        if (cum + c >= r) { s_sel = base + (uint32_t)j; s_rank = r - cum; break; }
        cum += c;
      }
    }
  }
  __syncthreads();
  uint32_t bsel = s_sel;
  uint32_t r = s_rank;                   // 1-indexed rank inside the bin
  uint32_t E = h[bsel];
  if (bsel == NBINS - 1u || E > BUCKET_CAP) {  // clamp bin or oversized bucket
    if (tid == 0u) hdr[HDR_FLAG] = 1u;         // -> exact fallback
    return;
  }
  // single pass: collect candidates in bin bsel (vectorized 2 per thread)
  const uint4* __restrict__ cand4 = (const uint4*)cand;
  uint32_t M2 = M >> 1;
  for (uint32_t j = tid; j < M2; j += 1024u) {
    uint4 c = cand4[j];
    if (bin_of(c.x) == bsel) { uint32_t p = atomicAdd(&s_bcnt, 1u); if (p < BUCKET_CAP) bkt[p] = make_uint2(c.x, c.y); }
    if (bin_of(c.z) == bsel) { uint32_t p = atomicAdd(&s_bcnt, 1u); if (p < BUCKET_CAP) bkt[p] = make_uint2(c.z, c.w); }
  }
  if (tid == 0u && (M & 1u)) {
    uint2 c = cand[M - 1u];
    if (bin_of(c.x) == bsel) { uint32_t p = atomicAdd(&s_bcnt, 1u); if (p < BUCKET_CAP) bkt[p] = c; }
  }
  __syncthreads();
  // exact selection: entry with composite rank r-1 (key desc, idx asc)
  for (uint32_t e = tid; e < E; e += 1024u) {
    uint2 me = bkt[e];
    uint32_t rank = 0u;
    for (uint32_t j = 0; j < E; ++j) {
      uint2 o = bkt[j];
      rank += (o.x > me.x || (o.x == me.x && o.y < me.y)) ? 1u : 0u;
    }
    if (rank == r - 1u) { hdr[HDR_THR] = me.x; hdr[HDR_ICUT] = me.y; }
  }
}

// Sparse scatter of kept candidates into the zeroed output.
__global__ __launch_bounds__(256) void k_scatter(
    const uint2* __restrict__ cand, const uint32_t* __restrict__ hdr,
    float* __restrict__ out, uint32_t cap) {
  if (hdr[HDR_FLAG] != 0u) return;
  uint32_t M = hdr[HDR_CURSOR]; if (M > cap) M = cap;
  uint32_t thr = hdr[HDR_THR], icut = hdr[HDR_ICUT];
  uint32_t stride = gridDim.x * blockDim.x;
  for (uint32_t i = blockIdx.x * blockDim.x + threadIdx.x; i < M; i += stride) {
    uint2 c = cand[i];
    if (c.x > thr || (c.x == thr && c.y <= icut)) out[c.y] = __uint_as_float(c.x);
  }
}

// Exact general fallback (gated; never taken for the fixed bench input).
// Single block, full radix select over all data + dense rewrite. Slow but correct.
__global__ __launch_bounds__(1024) void k_fallback(
    const float* __restrict__ x, float* __restrict__ out,
    const int* __restrict__ kptr, const uint32_t* __restrict__ hdr, uint32_t n) {
  if (hdr[HDR_FLAG] == 0u) return;
  __shared__ uint32_t hist[2048];
  __shared__ uint32_t s_sel, s_rank, s_found, s_eqcnt, s_icut;
  __shared__ uint32_t eq_idx[4096];
  uint32_t tid = threadIdx.x;
  uint32_t K = (uint32_t)kptr[0] * ROWS;
  uint32_t prefix = 0u;
  uint32_t R = K;
  bool zero_thr = (K == 0u);
  for (int lvl = 0; lvl < 3 && !zero_thr; ++lvl) {
    uint32_t shift = (lvl == 0) ? 21u : (lvl == 1 ? 10u : 0u);
    uint32_t nb = (lvl == 2) ? 1024u : 2048u;
    for (uint32_t b = tid; b < nb; b += 1024u) hist[b] = 0u;
    __syncthreads();
    for (uint32_t i = tid; i < n; i += 1024u) {
      float v = x[i];
      uint32_t key = (v > 0.f) ? __float_as_uint(v) : 0u;
      bool valid = (key != 0u);
      if (lvl == 1) valid = valid && ((key >> 21) == prefix);
      if (lvl == 2) valid = valid && ((key >> 10) == prefix);
      if (valid) atomicAdd(&hist[(key >> shift) & (nb - 1u)], 1u);
    }
    __syncthreads();
    if (tid == 0u) {
      uint32_t cum = 0u, sel = 0u, rr = R, found = 0u;
      for (int b = (int)nb - 1; b >= 0; --b) {
        uint32_t c = hist[b];
        if (cum + c >= R) { sel = (uint32_t)b; rr = R - cum; found = 1u; break; }
        cum += c;
      }
      s_sel = sel; s_rank = rr; s_found = found;
    }
    __syncthreads();
    if (s_found == 0u) {
      zero_thr = true;  // fewer than K positives: keep all positives
    } else {
      uint32_t sel = s_sel;
      R = s_rank;
      if (lvl == 0) prefix = sel;
      else if (lvl == 1) prefix = (prefix << 11) | sel;
      else prefix = (prefix << 10) | sel;
    }
    __syncthreads();
  }
  uint32_t thr_key = zero_thr ? 0u : prefix;
  uint32_t icut = 0xFFFFFFFFu;
  if (!zero_thr) {
    uint32_t E = hist[thr_key & 1023u];
    uint32_t T = R;
    if (T < E) {
      if (tid == 0u) { s_eqcnt = 0u; s_icut = 0xFFFFFFFFu; }
      __syncthreads();
      for (uint32_t i = tid; i < n; i += 1024u) {
        float v = x[i];
        if (v > 0.f && __float_as_uint(v) == thr_key) {
          uint32_t p = atomicAdd(&s_eqcnt, 1u);
          if (p < 4096u) eq_idx[p] = i;
        }
      }
      __syncthreads();
      uint32_t ec = s_eqcnt < 4096u ? s_eqcnt : 4096u;
      for (uint32_t e = tid; e < ec; e += 1024u) {
        uint32_t me = eq_idx[e];
        uint32_t rank = 0u;
        for (uint32_t j = 0; j < ec; ++j) rank += (eq_idx[j] < me) ? 1u : 0u;
        if (rank == T - 1u) s_icut = me;
      }
      __syncthreads();
      icut = s_icut;
    }
  }
  for (uint32_t i = tid; i < n; i += 1024u) {
    float v = x[i];
    uint32_t key = (v > 0.f) ? __float_as_uint(v) : 0u;
    bool keep = (key > thr_key) || (key != 0u && key == thr_key && i <= icut);
    out[i] = keep ? v : 0.f;
  }
}

extern "C" void kernel_launch(void* const* d_in, const int* in_sizes, int n_in,
                              void* d_out, int out_size, void* d_ws, size_t ws_size,
                              hipStream_t stream) {
  const float* x = (const float*)d_in[0];
  const int* kptr = (const int*)d_in[1];
  float* out = (float*)d_out;
  uint32_t n = (uint32_t)in_sizes[0];
  uint32_t n4 = n >> 2;

  uint32_t* hdr = (uint32_t*)d_ws;
  uint32_t* ghist = (uint32_t*)((char*)d_ws + HIST_OFF);
  uint2* cand = (uint2*)((char*)d_ws + CAND_OFF);
  uint32_t cap = (ws_size > (size_t)CAND_OFF) ? (uint32_t)((ws_size - CAND_OFF) / 8) : 0u;
  // If ws can't hold candidates with margin, force the exact fallback path.
  uint32_t force = (cap < 131072u) ? 1u : 0u;

  const uint32_t HALF = 2048u;  // blocks per role; grid = 2*HALF, parity-interleaved
  k_init<<<1, 256, 0, stream>>>(hdr, ghist, force);
  k_zero_scan<<<2u * HALF, 256, 0, stream>>>((float4*)out, out, (const float4*)x, x,
                                             cand, hdr, ghist, cap, n4, n, HALF);
  k_select<<<1, 1024, 0, stream>>>(cand, hdr, ghist, kptr, cap);
  k_fallback<<<1, 1024, 0, stream>>>(x, out, kptr, hdr, n);
  k_scatter<<<256, 256, 0, stream>>>(cand, hdr, out, cap);
}